// Round 1
// baseline (293.826 us; speedup 1.0000x reference)
//
#include <hip/hip_runtime.h>
#include <hip/hip_bf16.h>

#define C_DIM 320
#define N_DIM 4096   // = K = D*H*W
#define NEG_SLOPE 0.01f

typedef float f32x4 __attribute__((ext_vector_type(4)));
typedef short bf16x8 __attribute__((ext_vector_type(8)));
typedef __bf16 bfv8 __attribute__((ext_vector_type(8)));

__device__ __forceinline__ float lrelu(float e) { return fmaxf(e, NEG_SLOPE * e); }

// ---- kernel 1: s1[b,n] = sum_c p[b,c,n]*w1[c];  s2 likewise with w2 ----
__global__ __launch_bounds__(256) void k_s12(const float* __restrict__ x,
                                             const float* __restrict__ W,
                                             float* __restrict__ s1,
                                             float* __restrict__ s2) {
    int b = blockIdx.y;
    int n = blockIdx.x * 256 + threadIdx.x;
    const float* px = x + ((size_t)b * C_DIM) * N_DIM + n;
    float a1 = 0.f, a2 = 0.f;
    #pragma unroll 4
    for (int c = 0; c < C_DIM; ++c) {
        float v = px[(size_t)c * N_DIM];
        a1 = fmaf(v, W[c], a1);
        a2 = fmaf(v, W[C_DIM + c], a2);
    }
    s1[b * N_DIM + n] = a1;
    s2[b * N_DIM + n] = a2;
}

// ---- kernel 2: s1max[b] = max_k s1[b,k] ----
__global__ __launch_bounds__(256) void k_max(const float* __restrict__ s1,
                                             float* __restrict__ s1max) {
    __shared__ float red[256];
    int b = blockIdx.x;
    int tid = threadIdx.x;
    float mx = -3.4e38f;
    for (int k = tid; k < N_DIM; k += 256) mx = fmaxf(mx, s1[b * N_DIM + k]);
    red[tid] = mx;
    __syncthreads();
    for (int s = 128; s > 0; s >>= 1) {
        if (tid < s) red[tid] = fmaxf(red[tid], red[tid + s]);
        __syncthreads();
    }
    if (tid == 0) s1max[b] = red[0];
}

// ---- kernel 3: per row (b,n): m = lrelu(s2+s1max); rZ = 1/sum_k exp(lrelu(s2+s1[k])-m)
// one wave per row, 4 waves per block
__global__ __launch_bounds__(256) void k_z(const float* __restrict__ s1,
                                           const float* __restrict__ s2,
                                           const float* __restrict__ s1max,
                                           float* __restrict__ mArr,
                                           float* __restrict__ rZ) {
    int w = threadIdx.x >> 6, l = threadIdx.x & 63;
    int row = blockIdx.x * 4 + w;      // 0..8191  (b*4096+n)
    int b = row >> 12;
    const float* s1b = s1 + b * N_DIM;
    float s2n = s2[row];
    float mn = lrelu(s2n + s1max[b]);
    float sum = 0.f;
    for (int k = l; k < N_DIM; k += 64)
        sum += __expf(lrelu(s2n + s1b[k]) - mn);
    #pragma unroll
    for (int off = 32; off > 0; off >>= 1) sum += __shfl_down(sum, off);
    if (l == 0) { mArr[row] = mn; rZ[row] = 1.f / sum; }
}

// ---- kernel 4: fused GEMM  out[b,c,n] = sum_k P[c,k]*Q[k,n] + P[c,n]
// Q[k,n] = exp(lrelu(s2[n]+s1[k]) - m[n]) * rZ[n], generated in registers.
// WG tile 64(c) x 128(n); 4 waves, each 64x32 (4 M-frags x 2 N-frags), BK=32.
__global__ __launch_bounds__(256) void k_gemm(const float* __restrict__ x,
                                              const float* __restrict__ s1,
                                              const float* __restrict__ s2,
                                              const float* __restrict__ mArr,
                                              const float* __restrict__ rZ,
                                              float* __restrict__ out) {
    const int b  = blockIdx.z;
    const int c0 = blockIdx.y * 64;
    const int n0 = blockIdx.x * 128;
    const int tid = threadIdx.x;
    const int w  = tid >> 6;
    const int l  = tid & 63;
    const int lr = l & 15;   // row/col within 16x16 frag
    const int g  = l >> 4;   // k-group

    const float* pb  = x  + (size_t)b * C_DIM * N_DIM;
    const float* s1b = s1 + b * N_DIM;

    // per-lane B-column constants (hoisted out of K loop)
    int   ncol[2];
    float s2c[2], mc[2], rzc[2];
    #pragma unroll
    for (int t = 0; t < 2; ++t) {
        int n = n0 + w * 32 + t * 16 + lr;
        ncol[t] = n;
        s2c[t] = s2[b * N_DIM + n];
        mc[t]  = mArr[b * N_DIM + n];
        rzc[t] = rZ[b * N_DIM + n];
    }

    f32x4 acc[4][2];
    #pragma unroll
    for (int i = 0; i < 4; ++i)
        #pragma unroll
        for (int t = 0; t < 2; ++t)
            acc[i][t] = (f32x4){0.f, 0.f, 0.f, 0.f};

    for (int k0 = 0; k0 < N_DIM; k0 += 32) {
        const int kk = k0 + g * 8;
        // s1 slice for this lane's 8 k-values (broadcast across 16-lane groups)
        f32x4 s1lo = *(const f32x4*)(s1b + kk);
        f32x4 s1hi = *(const f32x4*)(s1b + kk + 4);

        // A fragments: P rows c0+16i+lr, 8 consecutive k, fp32 -> bf16
        bf16x8 afrag[4];
        #pragma unroll
        for (int i = 0; i < 4; ++i) {
            const float* ap = pb + (size_t)(c0 + i * 16 + lr) * N_DIM + kk;
            f32x4 lo = *(const f32x4*)ap;
            f32x4 hi = *(const f32x4*)(ap + 4);
            bfv8 av;
            #pragma unroll
            for (int j = 0; j < 4; ++j) { av[j] = (__bf16)lo[j]; av[j + 4] = (__bf16)hi[j]; }
            afrag[i] = __builtin_bit_cast(bf16x8, av);
        }

        // B fragments: Q generated on the fly
        bf16x8 bfrag[2];
        #pragma unroll
        for (int t = 0; t < 2; ++t) {
            bfv8 qv;
            #pragma unroll
            for (int j = 0; j < 8; ++j) {
                float s1k = (j < 4) ? s1lo[j] : s1hi[j - 4];
                float e = s2c[t] + s1k;
                float q = __expf(lrelu(e) - mc[t]) * rzc[t];
                qv[j] = (__bf16)q;
            }
            bfrag[t] = __builtin_bit_cast(bf16x8, qv);
        }

        #pragma unroll
        for (int i = 0; i < 4; ++i)
            #pragma unroll
            for (int t = 0; t < 2; ++t)
                acc[i][t] = __builtin_amdgcn_mfma_f32_16x16x32_bf16(
                    afrag[i], bfrag[t], acc[i][t], 0, 0, 0);
    }

    // epilogue: C/D map col = lane&15 (n), row = (lane>>4)*4 + reg (c); add residual p
    #pragma unroll
    for (int i = 0; i < 4; ++i)
        #pragma unroll
        for (int t = 0; t < 2; ++t)
            #pragma unroll
            for (int r = 0; r < 4; ++r) {
                int c = c0 + i * 16 + g * 4 + r;
                size_t idx = ((size_t)(b * C_DIM + c)) * N_DIM + ncol[t];
                out[idx] = acc[i][t][r] + x[idx];
            }
}

extern "C" void kernel_launch(void* const* d_in, const int* in_sizes, int n_in,
                              void* d_out, int out_size, void* d_ws, size_t ws_size,
                              hipStream_t stream) {
    const float* x = (const float*)d_in[0];
    const float* W = (const float*)d_in[1];
    float* out = (float*)d_out;

    float* ws    = (float*)d_ws;
    float* s1    = ws;            // 8192
    float* s2    = ws + 8192;     // 8192
    float* mArr  = ws + 16384;    // 8192
    float* rZ    = ws + 24576;    // 8192
    float* s1max = ws + 32768;    // 2

    k_s12 <<<dim3(N_DIM / 256, 2), 256, 0, stream>>>(x, W, s1, s2);
    k_max <<<2, 256, 0, stream>>>(s1, s1max);
    k_z   <<<(2 * N_DIM) / 4, 256, 0, stream>>>(s1, s2, s1max, mArr, rZ);
    k_gemm<<<dim3(N_DIM / 128, C_DIM / 64, 2), 256, 0, stream>>>(x, s1, s2, mArr, rZ, out);
}

// Round 2
// 97.292 us; speedup vs baseline: 3.0201x; 3.0201x over previous
//
#include <hip/hip_runtime.h>
#include <hip/hip_bf16.h>

#define C_DIM 320
#define N_DIM 4096
#define NEG 0.01f

typedef float f32x4 __attribute__((ext_vector_type(4)));
typedef short bf16x8 __attribute__((ext_vector_type(8)));
typedef __bf16 bfv8 __attribute__((ext_vector_type(8)));

__device__ __forceinline__ float lrelu(float e) { return fmaxf(e, NEG * e); }

__device__ __forceinline__ void gload_lds16(const void* g, void* l) {
    __builtin_amdgcn_global_load_lds(
        (const __attribute__((address_space(1))) void*)g,
        (__attribute__((address_space(3))) void*)l, 16, 0, 0);
}

// ===================== fast path =====================

// s1/s2 dot products + bf16 conversion of x (single pass over x)
__global__ __launch_bounds__(256) void k_s12(const float* __restrict__ x,
                                             const float* __restrict__ W,
                                             float* __restrict__ s1,
                                             float* __restrict__ s2,
                                             short* __restrict__ xb) {
    int b = blockIdx.y;
    int nl = threadIdx.x & 63, cq = threadIdx.x >> 6;
    int n = blockIdx.x * 64 + nl;
    const float* px = x + ((size_t)b * C_DIM + cq * 80) * N_DIM + n;
    short* pxb = xb + ((size_t)b * C_DIM + cq * 80) * N_DIM + n;
    const float* w1 = W + cq * 80;
    const float* w2 = W + C_DIM + cq * 80;
    float a1 = 0.f, a2 = 0.f;
    #pragma unroll 8
    for (int cc = 0; cc < 80; ++cc) {
        float v = px[(size_t)cc * N_DIM];
        a1 = fmaf(v, w1[cc], a1);
        a2 = fmaf(v, w2[cc], a2);
        __hip_bfloat16 hv = __float2bfloat16(v);
        pxb[(size_t)cc * N_DIM] = *(short*)&hv;
    }
    __shared__ float r1[4][64], r2[4][64];
    r1[cq][nl] = a1; r2[cq][nl] = a2;
    __syncthreads();
    if (threadIdx.x < 64) {
        float t1 = r1[0][nl] + r1[1][nl] + r1[2][nl] + r1[3][nl];
        float t2 = r2[0][nl] + r2[1][nl] + r2[2][nl] + r2[3][nl];
        s1[b * N_DIM + n] = t1;
        s2[b * N_DIM + n] = t2;
    }
}

__global__ __launch_bounds__(256) void k_max(const float* __restrict__ s1,
                                             float* __restrict__ s1max) {
    __shared__ float red[256];
    int b = blockIdx.x, tid = threadIdx.x;
    float mx = -3.4e38f;
    for (int k = tid; k < N_DIM; k += 256) mx = fmaxf(mx, s1[b * N_DIM + k]);
    red[tid] = mx;
    __syncthreads();
    for (int s = 128; s > 0; s >>= 1) {
        if (tid < s) red[tid] = fmaxf(red[tid], red[tid + s]);
        __syncthreads();
    }
    if (tid == 0) s1max[b] = red[0];
}

// Ek = exp(s1), Gk = exp(0.01*s1)
__global__ __launch_bounds__(256) void k_aux(const float* __restrict__ s1,
                                             float* __restrict__ Ek,
                                             float* __restrict__ Gk) {
    int gid = blockIdx.x * 256 + threadIdx.x;  // 0..8191
    float v = s1[gid];
    Ek[gid] = __expf(v);
    Gk[gid] = __expf(NEG * v);
}

// per row: Z = sum_k max(Ek*F, Gk*H); store Fz=F/Z, Hz=H/Z
__global__ __launch_bounds__(256) void k_z(const float* __restrict__ s2,
                                           const float* __restrict__ s1max,
                                           const float* __restrict__ Ek,
                                           const float* __restrict__ Gk,
                                           float* __restrict__ Fz,
                                           float* __restrict__ Hz) {
    int w = threadIdx.x >> 6, l = threadIdx.x & 63;
    int row = blockIdx.x * 4 + w;
    int b = row >> 12;
    float s2n = s2[row];
    float mn = lrelu(s2n + s1max[b]);
    float F = __expf(s2n - mn), H = __expf(NEG * s2n - mn);
    const float* Ekb = Ek + b * N_DIM;
    const float* Gkb = Gk + b * N_DIM;
    float sum = 0.f;
    for (int k = l; k < N_DIM; k += 64)
        sum += fmaxf(Ekb[k] * F, Gkb[k] * H);
    #pragma unroll
    for (int off = 32; off > 0; off >>= 1) sum += __shfl_down(sum, off);
    if (l == 0) {
        float rz = 1.f / sum;
        Fz[row] = F * rz;
        Hz[row] = H * rz;
    }
}

// fused GEMM: out[b,c,n] = sum_k P[c,k]*Q[k,n] + P[c,n]
// Q[k,n] = max(Ek[k]*Fz[n], Gk[k]*Hz[n]) (bf16), generated in registers.
// 512 thr = 8 waves: waves 0-3 K in [0,2048), 4-7 K in [2048,4096); wave tile 64c x 32n.
// A staged bf16 via global_load_lds (XOR-swizzled source, swizzled ds_read), dbuf.
__global__ __launch_bounds__(512) void k_gemm(const short* __restrict__ xb,
                                              const float* __restrict__ x,
                                              const float* __restrict__ Ek,
                                              const float* __restrict__ Gk,
                                              const float* __restrict__ Fz,
                                              const float* __restrict__ Hz,
                                              float* __restrict__ out) {
    __shared__ __align__(16) short Asm[2][2][4096];  // [khalf][dbuf][64*64] = 32 KB

    const int b = blockIdx.z, c0 = blockIdx.y * 64, n0 = blockIdx.x * 128;
    const int tid = threadIdx.x;
    const int w = tid >> 6, l = tid & 63, lr = l & 15, g = l >> 4;
    const int h = w >> 2, q = w & 3;
    const short* xbp = xb + (size_t)b * C_DIM * N_DIM;
    const float* Ekb = Ek + b * N_DIM;
    const float* Gkb = Gk + b * N_DIM;
    const int kbase = h * 2048;

    int ncol[2]; float fz[2], hz[2];
    #pragma unroll
    for (int t = 0; t < 2; ++t) {
        int n = n0 + q * 32 + t * 16 + lr;
        ncol[t] = n;
        fz[t] = Fz[b * N_DIM + n];
        hz[t] = Hz[b * N_DIM + n];
    }

    f32x4 acc[4][2];
    #pragma unroll
    for (int i = 0; i < 4; ++i)
        #pragma unroll
        for (int t = 0; t < 2; ++t)
            acc[i][t] = (f32x4){0.f, 0.f, 0.f, 0.f};

    // stage one 64x64 bf16 tile for this khalf into Asm[h][buf]
    auto stage = [&](int buf, int k0) {
        #pragma unroll
        for (int i = 0; i < 2; ++i) {
            int j = q * 128 + i * 64 + l;            // 0..511, 16B granule idx
            int row = j >> 3;
            int c8 = (j & 7) ^ (row & 7);            // pre-swizzled source granule
            const short* gp = xbp + (size_t)(c0 + row) * N_DIM + (kbase + k0 + c8 * 8);
            gload_lds16(gp, &Asm[h][buf][(q * 128 + i * 64) * 8]);
        }
    };

    stage(0, 0);
    __syncthreads();
    int cur = 0;
    for (int it = 0; it < 32; ++it) {
        if (it + 1 < 32) stage(cur ^ 1, (it + 1) * 64);
        const short* Ab = Asm[h][cur];
        #pragma unroll
        for (int s = 0; s < 2; ++s) {
            int k = kbase + it * 64 + s * 32 + g * 8;
            f32x4 e0 = *(const f32x4*)&Ekb[k];
            f32x4 e1 = *(const f32x4*)&Ekb[k + 4];
            f32x4 g0 = *(const f32x4*)&Gkb[k];
            f32x4 g1 = *(const f32x4*)&Gkb[k + 4];
            bf16x8 afr[4];
            #pragma unroll
            for (int i = 0; i < 4; ++i) {
                int row = 16 * i + lr;
                int idx = row * 64 + (((4 * s + g) ^ (row & 7)) * 8);
                afr[i] = *(const bf16x8*)&Ab[idx];
            }
            bf16x8 bfr[2];
            #pragma unroll
            for (int t = 0; t < 2; ++t) {
                bfv8 qv;
                #pragma unroll
                for (int jj = 0; jj < 4; ++jj) {
                    qv[jj]     = (__bf16)fmaxf(e0[jj] * fz[t], g0[jj] * hz[t]);
                    qv[jj + 4] = (__bf16)fmaxf(e1[jj] * fz[t], g1[jj] * hz[t]);
                }
                bfr[t] = __builtin_bit_cast(bf16x8, qv);
            }
            #pragma unroll
            for (int i = 0; i < 4; ++i)
                #pragma unroll
                for (int t = 0; t < 2; ++t)
                    acc[i][t] = __builtin_amdgcn_mfma_f32_16x16x32_bf16(
                        afr[i], bfr[t], acc[i][t], 0, 0, 0);
        }
        __syncthreads();
        cur ^= 1;
    }

    // in-block K-split reduction through LDS (reuse staging buffer), + residual
    float* red = (float*)&Asm[0][0][0];  // 8192 floats
    if (h == 1) {
        #pragma unroll
        for (int i = 0; i < 4; ++i)
            #pragma unroll
            for (int t = 0; t < 2; ++t)
                #pragma unroll
                for (int r = 0; r < 4; ++r)
                    red[q * 2048 + (i * 2 + t) * 256 + (g * 4 + r) * 16 + lr] = acc[i][t][r];
    }
    __syncthreads();
    if (h == 0) {
        #pragma unroll
        for (int i = 0; i < 4; ++i)
            #pragma unroll
            for (int t = 0; t < 2; ++t)
                #pragma unroll
                for (int r = 0; r < 4; ++r) {
                    float v = acc[i][t][r] +
                              red[q * 2048 + (i * 2 + t) * 256 + (g * 4 + r) * 16 + lr];
                    int c = c0 + 16 * i + g * 4 + r;
                    size_t idx = ((size_t)(b * C_DIM + c)) * N_DIM + ncol[t];
                    out[idx] = v + x[idx];
                }
    }
}

// ===================== fallback path (round-1, proven) =====================

__global__ __launch_bounds__(256) void k_s12_fb(const float* __restrict__ x,
                                                const float* __restrict__ W,
                                                float* __restrict__ s1,
                                                float* __restrict__ s2) {
    int b = blockIdx.y;
    int n = blockIdx.x * 256 + threadIdx.x;
    const float* px = x + ((size_t)b * C_DIM) * N_DIM + n;
    float a1 = 0.f, a2 = 0.f;
    #pragma unroll 4
    for (int c = 0; c < C_DIM; ++c) {
        float v = px[(size_t)c * N_DIM];
        a1 = fmaf(v, W[c], a1);
        a2 = fmaf(v, W[C_DIM + c], a2);
    }
    s1[b * N_DIM + n] = a1;
    s2[b * N_DIM + n] = a2;
}

__global__ __launch_bounds__(256) void k_z_fb(const float* __restrict__ s1,
                                              const float* __restrict__ s2,
                                              const float* __restrict__ s1max,
                                              float* __restrict__ mArr,
                                              float* __restrict__ rZ) {
    int w = threadIdx.x >> 6, l = threadIdx.x & 63;
    int row = blockIdx.x * 4 + w;
    int b = row >> 12;
    const float* s1b = s1 + b * N_DIM;
    float s2n = s2[row];
    float mn = lrelu(s2n + s1max[b]);
    float sum = 0.f;
    for (int k = l; k < N_DIM; k += 64)
        sum += __expf(lrelu(s2n + s1b[k]) - mn);
    #pragma unroll
    for (int off = 32; off > 0; off >>= 1) sum += __shfl_down(sum, off);
    if (l == 0) { mArr[row] = mn; rZ[row] = 1.f / sum; }
}

__global__ __launch_bounds__(256) void k_gemm_fb(const float* __restrict__ x,
                                                 const float* __restrict__ s1,
                                                 const float* __restrict__ s2,
                                                 const float* __restrict__ mArr,
                                                 const float* __restrict__ rZ,
                                                 float* __restrict__ out) {
    const int b = blockIdx.z, c0 = blockIdx.y * 64, n0 = blockIdx.x * 128;
    const int tid = threadIdx.x;
    const int w = tid >> 6, l = tid & 63, lr = l & 15, g = l >> 4;
    const float* pb = x + (size_t)b * C_DIM * N_DIM;
    const float* s1b = s1 + b * N_DIM;
    int ncol[2]; float s2c[2], mc[2], rzc[2];
    #pragma unroll
    for (int t = 0; t < 2; ++t) {
        int n = n0 + w * 32 + t * 16 + lr;
        ncol[t] = n; s2c[t] = s2[b * N_DIM + n];
        mc[t] = mArr[b * N_DIM + n]; rzc[t] = rZ[b * N_DIM + n];
    }
    f32x4 acc[4][2];
    #pragma unroll
    for (int i = 0; i < 4; ++i)
        #pragma unroll
        for (int t = 0; t < 2; ++t) acc[i][t] = (f32x4){0.f, 0.f, 0.f, 0.f};
    for (int k0 = 0; k0 < N_DIM; k0 += 32) {
        const int kk = k0 + g * 8;
        f32x4 s1lo = *(const f32x4*)(s1b + kk);
        f32x4 s1hi = *(const f32x4*)(s1b + kk + 4);
        bf16x8 afrag[4];
        #pragma unroll
        for (int i = 0; i < 4; ++i) {
            const float* ap = pb + (size_t)(c0 + i * 16 + lr) * N_DIM + kk;
            f32x4 lo = *(const f32x4*)ap;
            f32x4 hi = *(const f32x4*)(ap + 4);
            bfv8 av;
            #pragma unroll
            for (int j = 0; j < 4; ++j) { av[j] = (__bf16)lo[j]; av[j + 4] = (__bf16)hi[j]; }
            afrag[i] = __builtin_bit_cast(bf16x8, av);
        }
        bf16x8 bfrag[2];
        #pragma unroll
        for (int t = 0; t < 2; ++t) {
            bfv8 qv;
            #pragma unroll
            for (int j = 0; j < 8; ++j) {
                float s1k = (j < 4) ? s1lo[j] : s1hi[j - 4];
                float q = __expf(lrelu(s2c[t] + s1k) - mc[t]) * rzc[t];
                qv[j] = (__bf16)q;
            }
            bfrag[t] = __builtin_bit_cast(bf16x8, qv);
        }
        #pragma unroll
        for (int i = 0; i < 4; ++i)
            #pragma unroll
            for (int t = 0; t < 2; ++t)
                acc[i][t] = __builtin_amdgcn_mfma_f32_16x16x32_bf16(
                    afrag[i], bfrag[t], acc[i][t], 0, 0, 0);
    }
    #pragma unroll
    for (int i = 0; i < 4; ++i)
        #pragma unroll
        for (int t = 0; t < 2; ++t)
            #pragma unroll
            for (int r = 0; r < 4; ++r) {
                int c = c0 + i * 16 + g * 4 + r;
                size_t idx = ((size_t)(b * C_DIM + c)) * N_DIM + ncol[t];
                out[idx] = acc[i][t][r] + x[idx];
            }
}

// ===================== launch =====================

extern "C" void kernel_launch(void* const* d_in, const int* in_sizes, int n_in,
                              void* d_out, int out_size, void* d_ws, size_t ws_size,
                              hipStream_t stream) {
    const float* x = (const float*)d_in[0];
    const float* W = (const float*)d_in[1];
    float* out = (float*)d_out;
    float* ws = (float*)d_ws;

    const size_t need = (size_t)49168 * 4 + (size_t)2 * C_DIM * N_DIM * 2;
    if (ws_size >= need) {
        float* s1 = ws;
        float* s2 = ws + 8192;
        float* Ek = ws + 16384;
        float* Gk = ws + 24576;
        float* Fz = ws + 32768;
        float* Hz = ws + 40960;
        float* s1max = ws + 49152;
        short* xb = (short*)(ws + 49168);
        k_s12<<<dim3(64, 2), 256, 0, stream>>>(x, W, s1, s2, xb);
        k_max<<<2, 256, 0, stream>>>(s1, s1max);
        k_aux<<<32, 256, 0, stream>>>(s1, Ek, Gk);
        k_z<<<2048, 256, 0, stream>>>(s2, s1max, Ek, Gk, Fz, Hz);
        k_gemm<<<dim3(32, 5, 2), 512, 0, stream>>>(xb, x, Ek, Gk, Fz, Hz, out);
    } else {
        float* s1 = ws;
        float* s2 = ws + 8192;
        float* mArr = ws + 16384;
        float* rZ = ws + 24576;
        float* s1max = ws + 32768;
        k_s12_fb<<<dim3(N_DIM / 256, 2), 256, 0, stream>>>(x, W, s1, s2);
        k_max<<<2, 256, 0, stream>>>(s1, s1max);
        k_z_fb<<<(2 * N_DIM) / 4, 256, 0, stream>>>(s1, s2, s1max, mArr, rZ);
        k_gemm_fb<<<dim3(N_DIM / 128, C_DIM / 64, 2), 256, 0, stream>>>(x, s1, s2, mArr, rZ, out);
    }
}

// Round 3
// 75.489 us; speedup vs baseline: 3.8923x; 1.2888x over previous
//
#include <hip/hip_runtime.h>
#include <hip/hip_bf16.h>

#define C_DIM 320
#define N_DIM 4096
#define NEG 0.01f

typedef float f32x4 __attribute__((ext_vector_type(4)));
typedef short bf16x8 __attribute__((ext_vector_type(8)));
typedef __bf16 bfv8 __attribute__((ext_vector_type(8)));

__device__ __forceinline__ float lrelu(float e) { return fmaxf(e, NEG * e); }

__device__ __forceinline__ void gload_lds16(const void* g, void* l) {
    __builtin_amdgcn_global_load_lds(
        (const __attribute__((address_space(1))) void*)g,
        (__attribute__((address_space(3))) void*)l, 16, 0, 0);
}

// ===================== fast path =====================

// partial dot products (c-split 5) + bf16 conversion of x
// grid (64 n-blocks, 5 c-blocks, 2 b), 256 thr
__global__ __launch_bounds__(256) void k_s12(const float* __restrict__ x,
                                             const float* __restrict__ W,
                                             float* __restrict__ s1p,
                                             float* __restrict__ s2p,
                                             short* __restrict__ xb) {
    const int b = blockIdx.z, cb = blockIdx.y;
    const int nl = threadIdx.x & 63, cw = threadIdx.x >> 6;
    const int n = blockIdx.x * 64 + nl;
    const int cbase = cb * 64 + cw * 16;
    const float* px = x + ((size_t)b * C_DIM + cbase) * N_DIM + n;
    short* pxb = xb + ((size_t)b * C_DIM + cbase) * N_DIM + n;
    const float* w1 = W + cbase;
    const float* w2 = W + C_DIM + cbase;
    float a1 = 0.f, a2 = 0.f;
    #pragma unroll
    for (int cc = 0; cc < 16; ++cc) {
        float v = px[(size_t)cc * N_DIM];
        a1 = fmaf(v, w1[cc], a1);
        a2 = fmaf(v, w2[cc], a2);
        __hip_bfloat16 hv = __float2bfloat16(v);
        pxb[(size_t)cc * N_DIM] = *(short*)&hv;
    }
    __shared__ float r1[4][64], r2[4][64];
    r1[cw][nl] = a1; r2[cw][nl] = a2;
    __syncthreads();
    if (threadIdx.x < 64) {
        float t1 = r1[0][nl] + r1[1][nl] + r1[2][nl] + r1[3][nl];
        float t2 = r2[0][nl] + r2[1][nl] + r2[2][nl] + r2[3][nl];
        s1p[((size_t)b * 5 + cb) * N_DIM + n] = t1;
        s2p[((size_t)b * 5 + cb) * N_DIM + n] = t2;
    }
}

// fold 5 partials -> s2, Ek=exp(s1), Gk=exp(.01 s1), s1max (block reduce)
// grid (2), 1024 thr
__global__ __launch_bounds__(1024) void k_fold(const float* __restrict__ s1p,
                                               const float* __restrict__ s2p,
                                               float* __restrict__ s2,
                                               float* __restrict__ Ekf,
                                               float* __restrict__ Gkf,
                                               float* __restrict__ s1max) {
    const int b = blockIdx.x, tid = threadIdx.x;
    __shared__ float md[1024];
    float mx = -3.4e38f;
    for (int n = tid; n < N_DIM; n += 1024) {
        float v1 = 0.f, v2 = 0.f;
        #pragma unroll
        for (int cb = 0; cb < 5; ++cb) {
            v1 += s1p[((size_t)b * 5 + cb) * N_DIM + n];
            v2 += s2p[((size_t)b * 5 + cb) * N_DIM + n];
        }
        s2[b * N_DIM + n] = v2;
        Ekf[b * N_DIM + n] = __expf(v1);
        Gkf[b * N_DIM + n] = __expf(NEG * v1);
        mx = fmaxf(mx, v1);
    }
    md[tid] = mx;
    __syncthreads();
    for (int s = 512; s > 0; s >>= 1) {
        if (tid < s) md[tid] = fmaxf(md[tid], md[tid + s]);
        __syncthreads();
    }
    if (tid == 0) s1max[b] = logf(fmaxf(md[0], -3.4e38f)) * 0.f + md[0];
}

// per row: Z = sum_k max(Ek*F, Gk*H); store Fz=F/Z, Hz=H/Z.  E/G staged in LDS.
// grid (256, 2), 256 thr; block handles 16 rows (4/wave)
__global__ __launch_bounds__(256) void k_z(const float* __restrict__ s2,
                                           const float* __restrict__ s1max,
                                           const float* __restrict__ Ekf,
                                           const float* __restrict__ Gkf,
                                           float* __restrict__ Fz,
                                           float* __restrict__ Hz) {
    __shared__ __align__(16) float Els[4096], Gls[4096];
    const int b = blockIdx.y, tid = threadIdx.x;
    const int w = tid >> 6, l = tid & 63;
    const float* Eb = Ekf + b * N_DIM;
    const float* Gb = Gkf + b * N_DIM;
    #pragma unroll
    for (int i = 0; i < 4; ++i) {
        int ch = i * 256 + tid;
        *(f32x4*)&Els[ch * 4] = *(const f32x4*)&Eb[ch * 4];
        *(f32x4*)&Gls[ch * 4] = *(const f32x4*)&Gb[ch * 4];
    }
    __syncthreads();
    float smax = s1max[b];
    #pragma unroll
    for (int rr = 0; rr < 4; ++rr) {
        int row = b * N_DIM + blockIdx.x * 16 + w * 4 + rr;
        float s2n = s2[row];
        float mn = lrelu(s2n + smax);
        float F = __expf(s2n - mn), H = __expf(NEG * s2n - mn);
        float sum = 0.f;
        #pragma unroll 4
        for (int i = 0; i < 16; ++i) {
            int k = i * 256 + l * 4;
            f32x4 e = *(const f32x4*)&Els[k];
            f32x4 g = *(const f32x4*)&Gls[k];
            #pragma unroll
            for (int j = 0; j < 4; ++j) sum += fmaxf(e[j] * F, g[j] * H);
        }
        #pragma unroll
        for (int off = 32; off > 0; off >>= 1) sum += __shfl_down(sum, off);
        if (l == 0) {
            float rz = 1.f / sum;
            Fz[row] = F * rz;
            Hz[row] = H * rz;
        }
    }
}

// fused GEMM: out[b,c,n] = sum_k P[c,k]*Q[k,n] + P[c,n]
// Q[k,n] = max(Ek[k]*Fz[n], Gk[k]*Hz[n]) bf16, generated in registers.
// grid (64 n, 5 c, 2 b), 128 thr = 2 waves (K-halves). Wave tile 64c x 64n,
// per-wave PRIVATE LDS double-buffer, barrier-free K-loop w/ counted vmcnt.
__global__ __launch_bounds__(128) void k_gemm(const short* __restrict__ xb,
                                              const float* __restrict__ x,
                                              const float* __restrict__ Ekf,
                                              const float* __restrict__ Gkf,
                                              const float* __restrict__ Fz,
                                              const float* __restrict__ Hz,
                                              float* __restrict__ out) {
    __shared__ __align__(16) short Asm[2][2][4096];   // [wave][buf][64x64] 32 KB
    __shared__ __align__(16) float EGs[2][2][256];    // [wave][buf][E:0-63|G:64-127|pad]

    const int b = blockIdx.z, c0 = blockIdx.y * 64, n0 = blockIdx.x * 64;
    const int tid = threadIdx.x;
    const int h = tid >> 6, l = tid & 63, lr = l & 15, g = l >> 4;
    const short* xbp = xb + (size_t)b * C_DIM * N_DIM + h * 2048;
    const float* Eb = Ekf + b * N_DIM + h * 2048;
    const float* Gb = Gkf + b * N_DIM + h * 2048;

    int ncol[4]; float fz[4], hz[4];
    #pragma unroll
    for (int t = 0; t < 4; ++t) {
        int n = n0 + t * 16 + lr;
        ncol[t] = n;
        fz[t] = Fz[b * N_DIM + n];
        hz[t] = Hz[b * N_DIM + n];
    }

    f32x4 acc[4][4];
    #pragma unroll
    for (int i = 0; i < 4; ++i)
        #pragma unroll
        for (int t = 0; t < 4; ++t) acc[i][t] = (f32x4){0.f, 0.f, 0.f, 0.f};

    // stage A 64x64 bf16 tile (8 gload_lds) + EG slice (1 gload_lds) = 9 vmem ops
    auto stageA = [&](int buf, int it) {
        #pragma unroll
        for (int i = 0; i < 8; ++i) {
            int row = i * 8 + (l >> 3);
            int c8 = (l & 7) ^ (row & 7);          // pre-swizzled source granule
            gload_lds16(xbp + (size_t)(c0 + row) * N_DIM + it * 64 + c8 * 8,
                        &Asm[h][buf][i * 512]);
        }
    };
    auto stageEG = [&](int buf, int it) {
        int lm = l & 31;
        const float* p = (lm < 16) ? (Eb + it * 64 + lm * 4)
                                   : (Gb + it * 64 + (lm - 16) * 4);
        gload_lds16(p, &EGs[h][buf][0]);
    };

    stageA(0, 0); stageEG(0, 0);
    for (int it = 0; it < 32; ++it) {
        const int buf = it & 1;
        if (it < 31) {
            stageA(buf ^ 1, it + 1);
            stageEG(buf ^ 1, it + 1);
            asm volatile("s_waitcnt vmcnt(9)" ::: "memory");
        } else {
            asm volatile("s_waitcnt vmcnt(0)" ::: "memory");
        }
        __builtin_amdgcn_sched_barrier(0);
        #pragma unroll
        for (int s = 0; s < 2; ++s) {
            const int kk = s * 32 + g * 8;
            f32x4 e0 = *(const f32x4*)&EGs[h][buf][kk];
            f32x4 e1 = *(const f32x4*)&EGs[h][buf][kk + 4];
            f32x4 g0 = *(const f32x4*)&EGs[h][buf][64 + kk];
            f32x4 g1 = *(const f32x4*)&EGs[h][buf][64 + kk + 4];
            bf16x8 afr[4];
            #pragma unroll
            for (int i = 0; i < 4; ++i) {
                int row = 16 * i + lr;
                int idx = row * 64 + (((4 * s + g) ^ (row & 7)) * 8);
                afr[i] = *(const bf16x8*)&Asm[h][buf][idx];
            }
            bf16x8 bfr[4];
            #pragma unroll
            for (int t = 0; t < 4; ++t) {
                bfv8 qv;
                #pragma unroll
                for (int j = 0; j < 4; ++j) {
                    qv[j]     = (__bf16)fmaxf(e0[j] * fz[t], g0[j] * hz[t]);
                    qv[j + 4] = (__bf16)fmaxf(e1[j] * fz[t], g1[j] * hz[t]);
                }
                bfr[t] = __builtin_bit_cast(bf16x8, qv);
            }
            #pragma unroll
            for (int i = 0; i < 4; ++i)
                #pragma unroll
                for (int t = 0; t < 4; ++t)
                    acc[i][t] = __builtin_amdgcn_mfma_f32_16x16x32_bf16(
                        afr[i], bfr[t], acc[i][t], 0, 0, 0);
        }
    }

    // cross-wave K-reduction through LDS, + residual, write out
    __syncthreads();
    float* red = (float*)&Asm[0][0][0];   // 64 f32 per lane, 16 KB
    if (h == 1) {
        #pragma unroll
        for (int i = 0; i < 4; ++i)
            #pragma unroll
            for (int t = 0; t < 4; ++t)
                #pragma unroll
                for (int r = 0; r < 4; ++r)
                    red[((i * 4 + t) * 4 + r) * 64 + l] = acc[i][t][r];
    }
    __syncthreads();
    if (h == 0) {
        #pragma unroll
        for (int i = 0; i < 4; ++i)
            #pragma unroll
            for (int t = 0; t < 4; ++t)
                #pragma unroll
                for (int r = 0; r < 4; ++r) {
                    float v = acc[i][t][r] + red[((i * 4 + t) * 4 + r) * 64 + l];
                    int c = c0 + 16 * i + g * 4 + r;
                    size_t idx = ((size_t)(b * C_DIM + c)) * N_DIM + ncol[t];
                    out[idx] = v + x[idx];
                }
    }
}

// ===================== fallback path (round-1, proven) =====================

__global__ __launch_bounds__(256) void k_s12_fb(const float* __restrict__ x,
                                                const float* __restrict__ W,
                                                float* __restrict__ s1,
                                                float* __restrict__ s2) {
    int b = blockIdx.y;
    int n = blockIdx.x * 256 + threadIdx.x;
    const float* px = x + ((size_t)b * C_DIM) * N_DIM + n;
    float a1 = 0.f, a2 = 0.f;
    #pragma unroll 4
    for (int c = 0; c < C_DIM; ++c) {
        float v = px[(size_t)c * N_DIM];
        a1 = fmaf(v, W[c], a1);
        a2 = fmaf(v, W[C_DIM + c], a2);
    }
    s1[b * N_DIM + n] = a1;
    s2[b * N_DIM + n] = a2;
}

__global__ __launch_bounds__(256) void k_max_fb(const float* __restrict__ s1,
                                                float* __restrict__ s1max) {
    __shared__ float red[256];
    int b = blockIdx.x, tid = threadIdx.x;
    float mx = -3.4e38f;
    for (int k = tid; k < N_DIM; k += 256) mx = fmaxf(mx, s1[b * N_DIM + k]);
    red[tid] = mx;
    __syncthreads();
    for (int s = 128; s > 0; s >>= 1) {
        if (tid < s) red[tid] = fmaxf(red[tid], red[tid + s]);
        __syncthreads();
    }
    if (tid == 0) s1max[b] = red[0];
}

__global__ __launch_bounds__(256) void k_z_fb(const float* __restrict__ s1,
                                              const float* __restrict__ s2,
                                              const float* __restrict__ s1max,
                                              float* __restrict__ mArr,
                                              float* __restrict__ rZ) {
    int w = threadIdx.x >> 6, l = threadIdx.x & 63;
    int row = blockIdx.x * 4 + w;
    int b = row >> 12;
    const float* s1b = s1 + b * N_DIM;
    float s2n = s2[row];
    float mn = lrelu(s2n + s1max[b]);
    float sum = 0.f;
    for (int k = l; k < N_DIM; k += 64)
        sum += __expf(lrelu(s2n + s1b[k]) - mn);
    #pragma unroll
    for (int off = 32; off > 0; off >>= 1) sum += __shfl_down(sum, off);
    if (l == 0) { mArr[row] = mn; rZ[row] = 1.f / sum; }
}

__global__ __launch_bounds__(256) void k_gemm_fb(const float* __restrict__ x,
                                                 const float* __restrict__ s1,
                                                 const float* __restrict__ s2,
                                                 const float* __restrict__ mArr,
                                                 const float* __restrict__ rZ,
                                                 float* __restrict__ out) {
    const int b = blockIdx.z, c0 = blockIdx.y * 64, n0 = blockIdx.x * 128;
    const int tid = threadIdx.x;
    const int w = tid >> 6, l = tid & 63, lr = l & 15, g = l >> 4;
    const float* pb = x + (size_t)b * C_DIM * N_DIM;
    const float* s1b = s1 + b * N_DIM;
    int ncol[2]; float s2c[2], mc[2], rzc[2];
    #pragma unroll
    for (int t = 0; t < 2; ++t) {
        int n = n0 + w * 32 + t * 16 + lr;
        ncol[t] = n; s2c[t] = s2[b * N_DIM + n];
        mc[t] = mArr[b * N_DIM + n]; rzc[t] = rZ[b * N_DIM + n];
    }
    f32x4 acc[4][2];
    #pragma unroll
    for (int i = 0; i < 4; ++i)
        #pragma unroll
        for (int t = 0; t < 2; ++t) acc[i][t] = (f32x4){0.f, 0.f, 0.f, 0.f};
    for (int k0 = 0; k0 < N_DIM; k0 += 32) {
        const int kk = k0 + g * 8;
        f32x4 s1lo = *(const f32x4*)(s1b + kk);
        f32x4 s1hi = *(const f32x4*)(s1b + kk + 4);
        bf16x8 afrag[4];
        #pragma unroll
        for (int i = 0; i < 4; ++i) {
            const float* ap = pb + (size_t)(c0 + i * 16 + lr) * N_DIM + kk;
            f32x4 lo = *(const f32x4*)ap;
            f32x4 hi = *(const f32x4*)(ap + 4);
            bfv8 av;
            #pragma unroll
            for (int j = 0; j < 4; ++j) { av[j] = (__bf16)lo[j]; av[j + 4] = (__bf16)hi[j]; }
            afrag[i] = __builtin_bit_cast(bf16x8, av);
        }
        bf16x8 bfrag[2];
        #pragma unroll
        for (int t = 0; t < 2; ++t) {
            bfv8 qv;
            #pragma unroll
            for (int j = 0; j < 8; ++j) {
                float s1k = (j < 4) ? s1lo[j] : s1hi[j - 4];
                float q = __expf(lrelu(s2c[t] + s1k) - mc[t]) * rzc[t];
                qv[j] = (__bf16)q;
            }
            bfrag[t] = __builtin_bit_cast(bf16x8, qv);
        }
        #pragma unroll
        for (int i = 0; i < 4; ++i)
            #pragma unroll
            for (int t = 0; t < 2; ++t)
                acc[i][t] = __builtin_amdgcn_mfma_f32_16x16x32_bf16(
                    afrag[i], bfrag[t], acc[i][t], 0, 0, 0);
    }
    #pragma unroll
    for (int i = 0; i < 4; ++i)
        #pragma unroll
        for (int t = 0; t < 2; ++t)
            #pragma unroll
            for (int r = 0; r < 4; ++r) {
                int c = c0 + i * 16 + g * 4 + r;
                size_t idx = ((size_t)(b * C_DIM + c)) * N_DIM + ncol[t];
                out[idx] = acc[i][t][r] + x[idx];
            }
}

// ===================== launch =====================

extern "C" void kernel_launch(void* const* d_in, const int* in_sizes, int n_in,
                              void* d_out, int out_size, void* d_ws, size_t ws_size,
                              hipStream_t stream) {
    const float* x = (const float*)d_in[0];
    const float* W = (const float*)d_in[1];
    float* out = (float*)d_out;
    float* ws = (float*)d_ws;

    // layout (f32 offsets)
    const size_t o_s1p = 0, o_s2p = 40960, o_s2 = 81920, o_Ek = 90112,
                 o_Gk = 98304, o_Fz = 106496, o_Hz = 114688, o_mx = 122880,
                 o_xb = 122888;
    const size_t need = o_xb * 4 + (size_t)2 * C_DIM * N_DIM * 2;

    if (ws_size >= need) {
        float* s1p = ws + o_s1p;
        float* s2p = ws + o_s2p;
        float* s2  = ws + o_s2;
        float* Ekf = ws + o_Ek;
        float* Gkf = ws + o_Gk;
        float* Fz  = ws + o_Fz;
        float* Hz  = ws + o_Hz;
        float* s1max = ws + o_mx;
        short* xb = (short*)(ws + o_xb);
        k_s12 <<<dim3(64, 5, 2), 256, 0, stream>>>(x, W, s1p, s2p, xb);
        k_fold<<<2, 1024, 0, stream>>>(s1p, s2p, s2, Ekf, Gkf, s1max);
        k_z   <<<dim3(256, 2), 256, 0, stream>>>(s2, s1max, Ekf, Gkf, Fz, Hz);
        k_gemm<<<dim3(64, 5, 2), 128, 0, stream>>>(xb, x, Ekf, Gkf, Fz, Hz, out);
    } else {
        float* s1 = ws;
        float* s2 = ws + 8192;
        float* mArr = ws + 16384;
        float* rZ = ws + 24576;
        float* s1max = ws + 32768;
        k_s12_fb<<<dim3(N_DIM / 256, 2), 256, 0, stream>>>(x, W, s1, s2);
        k_max_fb<<<2, 256, 0, stream>>>(s1, s1max);
        k_z_fb<<<(2 * N_DIM) / 4, 256, 0, stream>>>(s1, s2, s1max, mArr, rZ);
        k_gemm_fb<<<dim3(N_DIM / 128, C_DIM / 64, 2), 256, 0, stream>>>(x, s1, s2, mArr, rZ, out);
    }
}